// Round 5
// baseline (194.709 us; speedup 1.0000x reference)
//
#include <hip/hip_runtime.h>
#include <hip/hip_bf16.h>

typedef __attribute__((ext_vector_type(8))) __bf16 bf16x8;
typedef __attribute__((ext_vector_type(4))) __bf16 bf16x4;
typedef __attribute__((ext_vector_type(4))) float f32x4;
typedef __attribute__((ext_vector_type(16))) float f32x16;

#define D_MODEL 768
#define SEQ     4096
#define NH      12
#define HD      64

// scale * log2(e), folded into Q at projection time
#define QSCALE (0.125f * 1.44269504088896f)

__device__ __forceinline__ void gload_lds16(const void* g, void* l) {
    __builtin_amdgcn_global_load_lds(
        (const __attribute__((address_space(1))) void*)g,
        (__attribute__((address_space(3))) void*)l, 16, 0, 0);
}

// ---------------------------------------------------------------------------
// Kernel 0: fp32 -> bf16 conversion
// ---------------------------------------------------------------------------
__global__ __launch_bounds__(256) void cvt_kernel(
    const float* __restrict__ x,  const float* __restrict__ wq,
    const float* __restrict__ wk, const float* __restrict__ wv,
    const float* __restrict__ wo,
    __bf16* __restrict__ xb,  __bf16* __restrict__ wqb,
    __bf16* __restrict__ wkb, __bf16* __restrict__ wvb,
    __bf16* __restrict__ wob)
{
    const int XV = SEQ * D_MODEL / 4;
    const int WV = D_MODEL * D_MODEL / 4;
    const int total = XV + 4 * WV;
    for (int i = blockIdx.x * blockDim.x + threadIdx.x; i < total;
         i += gridDim.x * blockDim.x) {
        const float* src; __bf16* dst; int j;
        if      (i < XV)          { src = x;  dst = xb;  j = i; }
        else if (i < XV + WV)     { src = wq; dst = wqb; j = i - XV; }
        else if (i < XV + 2*WV)   { src = wk; dst = wkb; j = i - XV - WV; }
        else if (i < XV + 3*WV)   { src = wv; dst = wvb; j = i - XV - 2*WV; }
        else                      { src = wo; dst = wob; j = i - XV - 3*WV; }
        float4 v = ((const float4*)src)[j];
        bf16x4 o;
        o[0] = (__bf16)v.x; o[1] = (__bf16)v.y;
        o[2] = (__bf16)v.z; o[3] = (__bf16)v.w;
        ((bf16x4*)dst)[j] = o;
    }
}

// ---------------------------------------------------------------------------
// Shared 128x128 BT-GEMM core, BK=64, global_load_lds staging, XOR swizzle.
// (identical to R3, which passed)
// ---------------------------------------------------------------------------
__device__ __forceinline__ void gemm128_core(
    const __bf16* __restrict__ A, const __bf16* __restrict__ B, int KD,
    f32x4 acc[4][4], __bf16 (*As)[64], __bf16 (*Bs)[64])
{
    const int t = threadIdx.x;
    const int lane = t & 63, wid = t >> 6;
    const int wm = (wid & 1) * 64, wn = (wid >> 1) * 64;
    const int lr = lane & 15, lc = lane >> 4;
    const int rl = lane >> 3;
    const int cs = (lane & 7) ^ rl;

    const __bf16* ag = A + (size_t)(wid * 32 + rl) * KD + cs * 8;
    const __bf16* bg = B + (size_t)(wid * 32 + rl) * KD + cs * 8;

    for (int kt = 0; kt < KD / 64; ++kt) {
        __syncthreads();
        #pragma unroll
        for (int i = 0; i < 4; ++i) {
            gload_lds16(ag + (size_t)i * 8 * KD + kt * 64,
                        &As[wid * 32 + i * 8][0]);
            gload_lds16(bg + (size_t)i * 8 * KD + kt * 64,
                        &Bs[wid * 32 + i * 8][0]);
        }
        __syncthreads();

        #pragma unroll
        for (int kh = 0; kh < 2; ++kh) {
            bf16x8 af[4], bfr[4];
            #pragma unroll
            for (int mi = 0; mi < 4; ++mi)
                af[mi] = *(const bf16x8*)
                    &As[wm + mi * 16 + lr][(((kh << 2) | lc) ^ (lr & 7)) * 8];
            #pragma unroll
            for (int ni = 0; ni < 4; ++ni)
                bfr[ni] = *(const bf16x8*)
                    &Bs[wn + ni * 16 + lr][(((kh << 2) | lc) ^ (lr & 7)) * 8];
            __builtin_amdgcn_s_setprio(1);
            #pragma unroll
            for (int mi = 0; mi < 4; ++mi)
                #pragma unroll
                for (int ni = 0; ni < 4; ++ni)
                    acc[mi][ni] = __builtin_amdgcn_mfma_f32_16x16x32_bf16(
                        af[mi], bfr[ni], acc[mi][ni], 0, 0, 0);
            __builtin_amdgcn_s_setprio(0);
        }
    }
}

// ---------------------------------------------------------------------------
// Kernel 1: fused QKV projection (R3-exact: dim3 grid, no swizzle)
// ---------------------------------------------------------------------------
__global__ __launch_bounds__(256) void qkv_gemm(
    const __bf16* __restrict__ xb,
    const __bf16* __restrict__ wqb, const __bf16* __restrict__ wkb,
    const __bf16* __restrict__ wvb,
    const float* __restrict__ bq, const float* __restrict__ bk,
    const float* __restrict__ bv,
    __bf16* __restrict__ Qo, __bf16* __restrict__ Ko,
    __bf16* __restrict__ Vto)
{
    __shared__ __bf16 As[128][64];
    __shared__ __bf16 Bs[128][64];
    const int bm = blockIdx.x;
    const int seg = blockIdx.y / 6, bn = blockIdx.y % 6;
    const __bf16* B  = (seg == 0) ? wqb : (seg == 1) ? wkb : wvb;
    const float* bias = (seg == 0) ? bq : (seg == 1) ? bk : bv;

    f32x4 acc[4][4] = {};
    gemm128_core(xb + (size_t)bm * 128 * D_MODEL,
                 B  + (size_t)bn * 128 * D_MODEL, D_MODEL, acc, As, Bs);

    const int t = threadIdx.x, lane = t & 63, wid = t >> 6;
    const int wm = (wid & 1) * 64, wn = (wid >> 1) * 64;
    const int lr = lane & 15, lc = lane >> 4;
    const int m0 = bm * 128 + wm, n0 = bn * 128 + wn;

    if (seg < 2) {
        __bf16* O = (seg == 0) ? Qo : Ko;
        const float sc = (seg == 0) ? QSCALE : 1.0f;
        #pragma unroll
        for (int mi = 0; mi < 4; ++mi)
            #pragma unroll
            for (int ni = 0; ni < 4; ++ni) {
                int col = n0 + ni * 16 + lr;
                float bb = bias[col];
                #pragma unroll
                for (int r = 0; r < 4; ++r)
                    O[(size_t)(m0 + mi * 16 + lc * 4 + r) * D_MODEL + col] =
                        (__bf16)((acc[mi][ni][r] + bb) * sc);
            }
    } else {
        #pragma unroll
        for (int mi = 0; mi < 4; ++mi)
            #pragma unroll
            for (int ni = 0; ni < 4; ++ni) {
                int col = n0 + ni * 16 + lr;
                float bb = bias[col];
                bf16x4 pk;
                #pragma unroll
                for (int r = 0; r < 4; ++r)
                    pk[r] = (__bf16)(acc[mi][ni][r] + bb);
                *(bf16x4*)&Vto[(size_t)col * SEQ + m0 + mi * 16 + lc * 4] = pk;
            }
    }
}

// ---------------------------------------------------------------------------
// Kernel 2: flash attention, 32x32 MFMA, 2 waves x 32 q-rows, KVBLK=64.
// Lane owns one q-row (q = lane&31). Softmax cross-half via __shfl_xor(32).
// P handed to PV via XOR-swizzled per-wave LDS (no permlane/cvtpk asm).
// ---------------------------------------------------------------------------
__global__ __launch_bounds__(128) void attn_kernel(
    const __bf16* __restrict__ Q, const __bf16* __restrict__ K,
    const __bf16* __restrict__ Vt, __bf16* __restrict__ Attn)
{
    __shared__ __bf16 Ks[2][64][64];   // [buf][kv][d]   chunk-XOR swizzled
    __shared__ __bf16 Vs[2][64][64];   // [buf][d][kv]
    __shared__ __bf16 Ps[2][32][64];   // [wave][q][kv]  chunk-XOR swizzled

    const int bid = blockIdx.x;                 // 768 = 8 * 96
    const int swz = (bid & 7) * 96 + (bid >> 3);
    const int h  = swz >> 6;
    const int q0 = (swz & 63) * 64;

    const int t = threadIdx.x, lane = t & 63, wid = t >> 6;
    const int ql = lane & 31;          // q-row within wave
    const int hi = lane >> 5;          // lane-half
    const int rl = lane >> 3;          // 0..7 (staging)
    const int cs = (lane & 7) ^ rl;    // staging source chunk (inverse swizzle)
    const int sx = lane & 7;           // frag-read chunk XOR ( = row&7 )

    const __bf16* kg = K  + (size_t)(wid * 32 + rl) * D_MODEL + h * HD + cs * 8;
    const __bf16* vg = Vt + (size_t)(h * HD + wid * 32 + rl) * SEQ + cs * 8;

    // Q fragments (B-operand): lane holds Q[q0+wid*32+ql][k4*16 + hi*8 + j]
    const __bf16* qrow = Q + (size_t)(q0 + wid * 32 + ql) * D_MODEL + h * HD;
    bf16x8 qf[4];
    #pragma unroll
    for (int k4 = 0; k4 < 4; ++k4)
        qf[k4] = *(const bf16x8*)&qrow[k4 * 16 + hi * 8];

    f32x16 acc0 = {}, acc1 = {};   // O^T[d][q]: d 0-31, 32-63
    float m_r = -1e30f, l_r = 0.f;

    // prologue: stage tile 0
    #pragma unroll
    for (int i = 0; i < 4; ++i) {
        gload_lds16(kg + (size_t)i * 8 * D_MODEL, &Ks[0][wid * 32 + i * 8][0]);
        gload_lds16(vg + (size_t)i * 8 * SEQ,     &Vs[0][wid * 32 + i * 8][0]);
    }

    // P write helper: pair (kvb, kvb+1), swizzled chunk
    #define PWRITE(kvb, v0, v1) do {                                         \
        union { __bf16 h2[2]; unsigned u; } t_;                              \
        t_.h2[0] = (__bf16)(v0); t_.h2[1] = (__bf16)(v1);                    \
        *(unsigned*)&Ps[wid][ql][((((kvb) >> 3) ^ sx) << 3) + ((kvb) & 7)]   \
            = t_.u;                                                          \
    } while (0)

    const int NT = SEQ / 64;
    for (int kt = 0; kt < NT; ++kt) {
        const int cur = kt & 1;
        __syncthreads();   // vmcnt(0) drain: tile kt landed; prev reads done

        if (kt + 1 < NT) {
            const int nxt = cur ^ 1;
            const __bf16* kgt = kg + (size_t)(kt + 1) * 64 * D_MODEL;
            const __bf16* vgt = vg + (size_t)(kt + 1) * 64;
            #pragma unroll
            for (int i = 0; i < 4; ++i) {
                gload_lds16(kgt + (size_t)i * 8 * D_MODEL,
                            &Ks[nxt][wid * 32 + i * 8][0]);
                gload_lds16(vgt + (size_t)i * 8 * SEQ,
                            &Vs[nxt][wid * 32 + i * 8][0]);
            }
        }

        // S^T = K Q^T (log2 domain): lane holds S[kv][q=ql],
        // kv = (r&3) + 8*(r>>2) + 4*hi   (+32 for st1)
        f32x16 st0 = {}, st1 = {};
        __builtin_amdgcn_s_setprio(1);
        #pragma unroll
        for (int k4 = 0; k4 < 4; ++k4) {
            bf16x8 kf0 = *(const bf16x8*)
                &Ks[cur][ql][((k4 * 2 + hi) ^ sx) * 8];
            bf16x8 kf1 = *(const bf16x8*)
                &Ks[cur][32 + ql][((k4 * 2 + hi) ^ sx) * 8];
            st0 = __builtin_amdgcn_mfma_f32_32x32x16_bf16(kf0, qf[k4], st0, 0, 0, 0);
            st1 = __builtin_amdgcn_mfma_f32_32x32x16_bf16(kf1, qf[k4], st1, 0, 0, 0);
        }
        __builtin_amdgcn_s_setprio(0);

        // ---- online softmax: lane-local + one shfl_xor(32) ----
        float mx = -1e30f;
        #pragma unroll
        for (int r = 0; r < 16; ++r) {
            mx = fmaxf(mx, st0[r]);
            mx = fmaxf(mx, st1[r]);
        }
        mx = fmaxf(mx, __shfl_xor(mx, 32, 64));

        const bool skip = (bool)__all(mx - m_r <= 8.0f);  // defer-max
        float mnew = skip ? m_r : fmaxf(m_r, mx);
        float corr = skip ? 1.0f : exp2f(m_r - mnew);

        float rs = 0.f;
        #pragma unroll
        for (int r = 0; r < 16; ++r) {
            st0[r] = exp2f(st0[r] - mnew);
            st1[r] = exp2f(st1[r] - mnew);
            rs += st0[r] + st1[r];
        }
        rs += __shfl_xor(rs, 32, 64);
        l_r = l_r * corr + rs;
        m_r = mnew;

        if (!skip) {
            #pragma unroll
            for (int r = 0; r < 16; ++r) { acc0[r] *= corr; acc1[r] *= corr; }
        }

        // ---- P -> per-wave LDS [q][kv], swizzled u32 pair writes ----
        #pragma unroll
        for (int qd = 0; qd < 4; ++qd) {
            PWRITE(8 * qd + 4 * hi,          st0[4 * qd + 0], st0[4 * qd + 1]);
            PWRITE(8 * qd + 4 * hi + 2,      st0[4 * qd + 2], st0[4 * qd + 3]);
            PWRITE(32 + 8 * qd + 4 * hi,     st1[4 * qd + 0], st1[4 * qd + 1]);
            PWRITE(32 + 8 * qd + 4 * hi + 2, st1[4 * qd + 2], st1[4 * qd + 3]);
        }

        // ---- PV: A = Vt rows (d), B = P[q][kv] from LDS, O^T accumulate ----
        __builtin_amdgcn_s_setprio(1);
        #pragma unroll
        for (int kp = 0; kp < 4; ++kp) {
            bf16x8 pf = *(const bf16x8*)
                &Ps[wid][ql][((kp * 2 + hi) ^ sx) * 8];
            bf16x8 vf0 = *(const bf16x8*)
                &Vs[cur][ql][((kp * 2 + hi) ^ sx) * 8];
            bf16x8 vf1 = *(const bf16x8*)
                &Vs[cur][32 + ql][((kp * 2 + hi) ^ sx) * 8];
            acc0 = __builtin_amdgcn_mfma_f32_32x32x16_bf16(vf0, pf, acc0, 0, 0, 0);
            acc1 = __builtin_amdgcn_mfma_f32_32x32x16_bf16(vf1, pf, acc1, 0, 0, 0);
        }
        __builtin_amdgcn_s_setprio(0);
    }
    #undef PWRITE

    // epilogue: O/l.  acc reg r -> d = (r&3) + 8*(r>>2) + 4*hi (+32 for acc1)
    float linv = 1.0f / l_r;
    __bf16* orow = Attn + (size_t)(q0 + wid * 32 + ql) * D_MODEL + h * HD + hi * 4;
    #pragma unroll
    for (int g = 0; g < 4; ++g) {
        union { __bf16 h4[4]; uint2 v2; } w;
        w.h4[0] = (__bf16)(acc0[g * 4 + 0] * linv);
        w.h4[1] = (__bf16)(acc0[g * 4 + 1] * linv);
        w.h4[2] = (__bf16)(acc0[g * 4 + 2] * linv);
        w.h4[3] = (__bf16)(acc0[g * 4 + 3] * linv);
        *(uint2*)&orow[g * 8] = w.v2;
        w.h4[0] = (__bf16)(acc1[g * 4 + 0] * linv);
        w.h4[1] = (__bf16)(acc1[g * 4 + 1] * linv);
        w.h4[2] = (__bf16)(acc1[g * 4 + 2] * linv);
        w.h4[3] = (__bf16)(acc1[g * 4 + 3] * linv);
        *(uint2*)&orow[32 + g * 8] = w.v2;
    }
}

// ---------------------------------------------------------------------------
// Kernel 3: output projection -> fp32 d_out (R3-exact)
// ---------------------------------------------------------------------------
__global__ __launch_bounds__(256) void out_gemm(
    const __bf16* __restrict__ Ab, const __bf16* __restrict__ wob,
    const float* __restrict__ bo, float* __restrict__ out)
{
    __shared__ __bf16 As[128][64];
    __shared__ __bf16 Bs[128][64];
    const int bm = blockIdx.x, bn = blockIdx.y;
    f32x4 acc[4][4] = {};
    gemm128_core(Ab  + (size_t)bm * 128 * D_MODEL,
                 wob + (size_t)bn * 128 * D_MODEL, D_MODEL, acc, As, Bs);

    const int t = threadIdx.x, lane = t & 63, wid = t >> 6;
    const int wm = (wid & 1) * 64, wn = (wid >> 1) * 64;
    const int lr = lane & 15, lc = lane >> 4;
    const int m0 = bm * 128 + wm, n0 = bn * 128 + wn;
    #pragma unroll
    for (int mi = 0; mi < 4; ++mi)
        #pragma unroll
        for (int ni = 0; ni < 4; ++ni) {
            int col = n0 + ni * 16 + lr;
            float bb = bo[col];
            #pragma unroll
            for (int r = 0; r < 4; ++r)
                out[(size_t)(m0 + mi * 16 + lc * 4 + r) * D_MODEL + col] =
                    acc[mi][ni][r] + bb;
        }
}

// ---------------------------------------------------------------------------
extern "C" void kernel_launch(void* const* d_in, const int* in_sizes, int n_in,
                              void* d_out, int out_size, void* d_ws, size_t ws_size,
                              hipStream_t stream) {
    const float* x  = (const float*)d_in[0];
    const float* wq = (const float*)d_in[1];
    const float* bq = (const float*)d_in[2];
    const float* wk = (const float*)d_in[3];
    const float* bk = (const float*)d_in[4];
    const float* wv = (const float*)d_in[5];
    const float* bv = (const float*)d_in[6];
    const float* wo = (const float*)d_in[7];
    const float* bo = (const float*)d_in[8];

    char* ws = (char*)d_ws;
    const size_t XB_SZ = (size_t)SEQ * D_MODEL * 2;
    const size_t W_SZ  = (size_t)D_MODEL * D_MODEL * 2;
    __bf16* xb  = (__bf16*)(ws);
    __bf16* wqb = (__bf16*)(ws + XB_SZ);
    __bf16* wkb = (__bf16*)(ws + XB_SZ + W_SZ);
    __bf16* wvb = (__bf16*)(ws + XB_SZ + 2 * W_SZ);
    __bf16* wob = (__bf16*)(ws + XB_SZ + 3 * W_SZ);
    __bf16* Qb  = (__bf16*)(ws + XB_SZ + 4 * W_SZ);
    __bf16* Kb  = (__bf16*)(ws + 2 * XB_SZ + 4 * W_SZ);
    __bf16* Vtb = (__bf16*)(ws + 3 * XB_SZ + 4 * W_SZ);
    __bf16* Ab  = (__bf16*)(ws + 4 * XB_SZ + 4 * W_SZ);

    cvt_kernel<<<1024, 256, 0, stream>>>(x, wq, wk, wv, wo,
                                         xb, wqb, wkb, wvb, wob);
    qkv_gemm<<<dim3(32, 18), 256, 0, stream>>>(xb, wqb, wkb, wvb,
                                               bq, bk, bv, Qb, Kb, Vtb);
    attn_kernel<<<768, 128, 0, stream>>>(Qb, Kb, Vtb, Ab);
    out_gemm<<<dim3(32, 6), 256, 0, stream>>>(Ab, wob, bo, (float*)d_out);
}